// Round 4
// baseline (280.203 us; speedup 1.0000x reference)
//
#include <hip/hip_runtime.h>

// ---- problem constants (match reference) ----
#define N_HALF   131072
#define MEM_ELEMS (64 * 512)
#define NIN      (2 * N_HALF + MEM_ELEMS + 1)   // 294913 input nodes (incl. bias)
#define NEDGES   16777216
#define NOUT     512
#define TPB      256

#define NGROUPS       (NEDGES / 4)              // 4,194,304 int4-groups
#define HALF_GROUPS   (NGROUPS / 2)             // 2,097,152
#define GPB           2048                      // groups per block (both variants)
#define NBLK_HALF     (HALF_GROUPS / GPB)       // 1024 blocks per half
#define NROWS         (2 * NBLK_HALF)           // 2048 partial rows total

// reduce params
#define RBLK          128
#define ROWS_PER_BLK  (NROWS / RBLK)            // 16

typedef int   vint4   __attribute__((ext_vector_type(4)));
typedef float vfloat4 __attribute__((ext_vector_type(4)));

// ---------------------------------------------------------------
// Stage 0: build x = [terrain, population, memory.flatten(), 1.0]
// and zero the 512-float output.
// ---------------------------------------------------------------
__global__ __launch_bounds__(TPB) void build_x_kernel(
    const float* __restrict__ terrain,
    const float* __restrict__ pop,
    const float* __restrict__ mem,
    float* __restrict__ x,
    float* __restrict__ out)
{
    int i = blockIdx.x * TPB + threadIdx.x;
    if (i < NOUT) out[i] = 0.0f;
    if (i >= NIN) return;
    float v;
    if (i < N_HALF)            v = terrain[i];
    else if (i < 2 * N_HALF)   v = pop[i - N_HALF];
    else if (i < NIN - 1)      v = mem[i - 2 * N_HALF];
    else                       v = 1.0f;
    x[i] = v;
}

__device__ __forceinline__ float fetch_direct(int s,
    const float* __restrict__ terrain,
    const float* __restrict__ pop,
    const float* __restrict__ mem)
{
    if (s < 2 * N_HALF)
        return (s < N_HALF) ? terrain[s] : pop[s - N_HALF];
    return (s < NIN - 1) ? mem[s - 2 * N_HALF] : 1.0f;
}

__global__ __launch_bounds__(TPB) void zero_out_kernel(float* __restrict__ out)
{
    int i = blockIdx.x * TPB + threadIdx.x;
    if (i < NOUT) out[i] = 0.0f;
}

// ---------------------------------------------------------------
// Deep-MLP edge kernel. Per rep, each thread keeps G int4-groups
// (4G edges) FULLY in flight: G src loads, then G dst + G w loads,
// then 4G gathers — only then consume. vmcnt retire order matches
// consume order, so each partial wait leaves the rest outstanding.
//   A: G=4, REPS=2 (16 edges in flight, ~100 VGPR)
//   B: G=8, REPS=1 (32 edges in flight, ~160 VGPR)
// ---------------------------------------------------------------
template <int G, int REPS>
__global__ __launch_bounds__(TPB) void edge_deep_kernel(
    const vint4*   __restrict__ src4,
    const vint4*   __restrict__ dst4,
    const vfloat4* __restrict__ w4,
    const float*   __restrict__ x,
    float* __restrict__ partials,
    int groupBase, int rowBase)
{
    __shared__ float acc[NOUT];
    const int t = threadIdx.x;
    acc[t] = 0.0f;
    acc[t + TPB] = 0.0f;
    __syncthreads();

    const int base = groupBase + blockIdx.x * GPB + t;

#pragma unroll
    for (int rep = 0; rep < REPS; ++rep) {
        const int rb = base + rep * (G * TPB);

        vint4   s[G];
        vint4   d[G];
        vfloat4 wv[G];
#pragma unroll
        for (int u = 0; u < G; ++u)
            s[u] = __builtin_nontemporal_load(&src4[rb + u * TPB]);
#pragma unroll
        for (int u = 0; u < G; ++u)
            d[u] = __builtin_nontemporal_load(&dst4[rb + u * TPB]);
#pragma unroll
        for (int u = 0; u < G; ++u)
            wv[u] = __builtin_nontemporal_load(&w4[rb + u * TPB]);

        float g[G][4];
#pragma unroll
        for (int u = 0; u < G; ++u) {
            g[u][0] = x[s[u].x];
            g[u][1] = x[s[u].y];
            g[u][2] = x[s[u].z];
            g[u][3] = x[s[u].w];
        }

#pragma unroll
        for (int u = 0; u < G; ++u) {
            unsafeAtomicAdd(&acc[d[u].x], g[u][0] * wv[u].x);
            unsafeAtomicAdd(&acc[d[u].y], g[u][1] * wv[u].y);
            unsafeAtomicAdd(&acc[d[u].z], g[u][2] * wv[u].z);
            unsafeAtomicAdd(&acc[d[u].w], g[u][3] * wv[u].w);
        }
    }
    __syncthreads();

    const size_t row = (size_t)(rowBase + blockIdx.x) * NOUT;
    partials[row + t]       = acc[t];
    partials[row + t + TPB] = acc[t + TPB];
}

// ---------------------------------------------------------------
// Fallback (small ws): simple gather + global atomics.
//   MODE 1: x prebuilt.  MODE 2: direct 3-way gather.
// ---------------------------------------------------------------
template <int MODE>
__global__ __launch_bounds__(TPB) void edge_fallback_kernel(
    const vint4*   __restrict__ src4,
    const vint4*   __restrict__ dst4,
    const vfloat4* __restrict__ w4,
    const float*   __restrict__ x,
    const float*   __restrict__ terrain,
    const float*   __restrict__ pop,
    const float*   __restrict__ mem,
    float* __restrict__ outp)
{
    __shared__ float acc[NOUT];
    const int t = threadIdx.x;
    acc[t] = 0.0f;
    acc[t + TPB] = 0.0f;
    __syncthreads();

    const int base = blockIdx.x * GPB + t;
    for (int j = 0; j < GPB / TPB; ++j) {
        const int gi = base + j * TPB;
        vint4   s = src4[gi];
        vint4   d = dst4[gi];
        vfloat4 w = w4[gi];
        float g0, g1, g2, g3;
        if (MODE == 2) {
            g0 = fetch_direct(s.x, terrain, pop, mem);
            g1 = fetch_direct(s.y, terrain, pop, mem);
            g2 = fetch_direct(s.z, terrain, pop, mem);
            g3 = fetch_direct(s.w, terrain, pop, mem);
        } else {
            g0 = x[s.x]; g1 = x[s.y]; g2 = x[s.z]; g3 = x[s.w];
        }
        unsafeAtomicAdd(&acc[d.x], g0 * w.x);
        unsafeAtomicAdd(&acc[d.y], g1 * w.y);
        unsafeAtomicAdd(&acc[d.z], g2 * w.z);
        unsafeAtomicAdd(&acc[d.w], g3 * w.w);
    }
    __syncthreads();
    unsafeAtomicAdd(&outp[t],       acc[t]);
    unsafeAtomicAdd(&outp[t + TPB], acc[t + TPB]);
}

// ---------------------------------------------------------------
// Stage 2: reduce partials[NROWS][512] -> out[512], coalesced.
// ---------------------------------------------------------------
__global__ __launch_bounds__(128) void reduce_kernel(
    const float* __restrict__ partials, float* __restrict__ out)
{
    const vfloat4* __restrict__ p4 = (const vfloat4*)partials;
    const int t  = threadIdx.x;                 // 0..127 float4-column
    const int r0 = blockIdx.x * ROWS_PER_BLK;
    vfloat4 s = {0.f, 0.f, 0.f, 0.f};
#pragma unroll
    for (int r = 0; r < ROWS_PER_BLK; ++r) {
        vfloat4 v = p4[(size_t)(r0 + r) * (NOUT / 4) + t];
        s += v;
    }
    unsafeAtomicAdd(&out[t * 4 + 0], s.x);
    unsafeAtomicAdd(&out[t * 4 + 1], s.y);
    unsafeAtomicAdd(&out[t * 4 + 2], s.z);
    unsafeAtomicAdd(&out[t * 4 + 3], s.w);
}

extern "C" void kernel_launch(void* const* d_in, const int* in_sizes, int n_in,
                              void* d_out, int out_size, void* d_ws, size_t ws_size,
                              hipStream_t stream)
{
    const float* terrain = (const float*)d_in[0];
    const float* pop     = (const float*)d_in[1];
    const float* mem     = (const float*)d_in[2];
    const int*   src     = (const int*)d_in[3];
    const int*   dst     = (const int*)d_in[4];
    const float* w       = (const float*)d_in[5];
    float* out = (float*)d_out;

    const size_t X_BYTES  = (size_t)NIN * 4;                      // 1,179,652
    const size_t PART_OFF = 1179904;                              // 256B aligned
    const size_t NEED     = PART_OFF + (size_t)NROWS * NOUT * 4;  // ~5.4 MB

    float* x        = (float*)d_ws;
    float* partials = (float*)((char*)d_ws + PART_OFF);

    if (ws_size >= NEED) {
        build_x_kernel<<<(NIN + TPB - 1) / TPB, TPB, 0, stream>>>(terrain, pop, mem, x, out);
        // Variant A: 16 edges in flight per thread (first half of edges)
        edge_deep_kernel<4, 2><<<NBLK_HALF, TPB, 0, stream>>>(
            (const vint4*)src, (const vint4*)dst, (const vfloat4*)w,
            x, partials, /*groupBase=*/0, /*rowBase=*/0);
        // Variant B: 32 edges in flight per thread (second half of edges)
        edge_deep_kernel<8, 1><<<NBLK_HALF, TPB, 0, stream>>>(
            (const vint4*)src, (const vint4*)dst, (const vfloat4*)w,
            x, partials, /*groupBase=*/HALF_GROUPS, /*rowBase=*/NBLK_HALF);
        reduce_kernel<<<RBLK, 128, 0, stream>>>(partials, out);
    } else if (ws_size >= X_BYTES) {
        build_x_kernel<<<(NIN + TPB - 1) / TPB, TPB, 0, stream>>>(terrain, pop, mem, x, out);
        edge_fallback_kernel<1><<<NGROUPS / GPB, TPB, 0, stream>>>(
            (const vint4*)src, (const vint4*)dst, (const vfloat4*)w,
            x, terrain, pop, mem, out);
    } else {
        zero_out_kernel<<<(NOUT + TPB - 1) / TPB, TPB, 0, stream>>>(out);
        edge_fallback_kernel<2><<<NGROUPS / GPB, TPB, 0, stream>>>(
            (const vint4*)src, (const vint4*)dst, (const vfloat4*)w,
            nullptr, terrain, pop, mem, out);
    }
}

// Round 5
// 262.125 us; speedup vs baseline: 1.0690x; 1.0690x over previous
//
#include <hip/hip_runtime.h>

// ---- problem constants (match reference) ----
#define N_HALF   131072
#define MEM_ELEMS (64 * 512)
#define NIN      (2 * N_HALF + MEM_ELEMS + 1)   // 294913 input nodes (incl. bias)
#define NEDGES   16777216
#define NOUT     512
#define TPB      256

#define NGROUPS   (NEDGES / 4)                  // 4,194,304 int4-groups
#define G         4                             // groups staged per thread (16 edges)
#define GPB       (TPB * G)                     // 1024 groups per block
#define NBLK_E    (NGROUPS / GPB)               // 4096 edge blocks (16 per CU)
#define NACC      32                            // global accumulation rows
#define ACC_FLOATS (NACC * NOUT)                // 16384 floats = 64 KB

typedef int   vint4   __attribute__((ext_vector_type(4)));
typedef float vfloat4 __attribute__((ext_vector_type(4)));

// ---------------------------------------------------------------
// Stage 0: build x = [terrain, population, memory.flatten(), 1.0],
// zero the 32x512 partial-accumulation rows.
// ---------------------------------------------------------------
__global__ __launch_bounds__(TPB) void build_x_kernel(
    const float* __restrict__ terrain,
    const float* __restrict__ pop,
    const float* __restrict__ mem,
    float* __restrict__ x,
    float* __restrict__ partials)
{
    int i = blockIdx.x * TPB + threadIdx.x;
    if (i < ACC_FLOATS) partials[i] = 0.0f;
    if (i >= NIN) return;
    float v;
    if (i < N_HALF)            v = terrain[i];
    else if (i < 2 * N_HALF)   v = pop[i - N_HALF];
    else if (i < NIN - 1)      v = mem[i - 2 * N_HALF];
    else                       v = 1.0f;
    x[i] = v;
}

__device__ __forceinline__ float fetch_direct(int s,
    const float* __restrict__ terrain,
    const float* __restrict__ pop,
    const float* __restrict__ mem)
{
    if (s < 2 * N_HALF)
        return (s < N_HALF) ? terrain[s] : pop[s - N_HALF];
    return (s < NIN - 1) ? mem[s - 2 * N_HALF] : 1.0f;
}

__global__ __launch_bounds__(TPB) void zero_out_kernel(float* __restrict__ out)
{
    int i = blockIdx.x * TPB + threadIdx.x;
    if (i < NOUT) out[i] = 0.0f;
}

// ---------------------------------------------------------------
// Edge kernel: 4096 blocks x 256 threads, 16 edges/thread fully
// staged (12 nt stream loads + 16 gathers in flight), per-wave LDS
// accumulators, block result merged by global f32 atomics into one
// of 32 partial rows.
// ---------------------------------------------------------------
__global__ __launch_bounds__(TPB) void edge_kernel(
    const vint4*   __restrict__ src4,
    const vint4*   __restrict__ dst4,
    const vfloat4* __restrict__ w4,
    const float*   __restrict__ x,
    float* __restrict__ partials)
{
    __shared__ float acc[4][NOUT];              // per-wave accumulators, 8 KB
    const int t   = threadIdx.x;
    const int wid = t >> 6;
#pragma unroll
    for (int k = 0; k < 8; ++k)
        acc[(t * 8 + k) >> 9][(t * 8 + k) & (NOUT - 1)] = 0.0f;
    __syncthreads();

    const int base = blockIdx.x * GPB + t;

    vint4   s[G];
    vint4   d[G];
    vfloat4 wv[G];
#pragma unroll
    for (int u = 0; u < G; ++u)
        s[u] = __builtin_nontemporal_load(&src4[base + u * TPB]);
#pragma unroll
    for (int u = 0; u < G; ++u)
        d[u] = __builtin_nontemporal_load(&dst4[base + u * TPB]);
#pragma unroll
    for (int u = 0; u < G; ++u)
        wv[u] = __builtin_nontemporal_load(&w4[base + u * TPB]);

    float g[G][4];
#pragma unroll
    for (int u = 0; u < G; ++u) {
        g[u][0] = x[s[u].x];
        g[u][1] = x[s[u].y];
        g[u][2] = x[s[u].z];
        g[u][3] = x[s[u].w];
    }

#pragma unroll
    for (int u = 0; u < G; ++u) {
        unsafeAtomicAdd(&acc[wid][d[u].x], g[u][0] * wv[u].x);
        unsafeAtomicAdd(&acc[wid][d[u].y], g[u][1] * wv[u].y);
        unsafeAtomicAdd(&acc[wid][d[u].z], g[u][2] * wv[u].z);
        unsafeAtomicAdd(&acc[wid][d[u].w], g[u][3] * wv[u].w);
    }
    __syncthreads();

    // Merge 4 wave accumulators; one global atomic per output slot.
    float* prow = partials + (size_t)(blockIdx.x & (NACC - 1)) * NOUT;
#pragma unroll
    for (int k = 0; k < 2; ++k) {
        const int slot = t + k * TPB;
        const float v = acc[0][slot] + acc[1][slot] + acc[2][slot] + acc[3][slot];
        unsafeAtomicAdd(&prow[slot], v);
    }
}

// ---------------------------------------------------------------
// Fallback (small ws): simple gather + global atomics.
// ---------------------------------------------------------------
template <int MODE>
__global__ __launch_bounds__(TPB) void edge_fallback_kernel(
    const vint4*   __restrict__ src4,
    const vint4*   __restrict__ dst4,
    const vfloat4* __restrict__ w4,
    const float*   __restrict__ x,
    const float*   __restrict__ terrain,
    const float*   __restrict__ pop,
    const float*   __restrict__ mem,
    float* __restrict__ outp)
{
    __shared__ float acc[NOUT];
    const int t = threadIdx.x;
    acc[t] = 0.0f;
    acc[t + TPB] = 0.0f;
    __syncthreads();

    const int base = blockIdx.x * GPB + t;
    for (int j = 0; j < G; ++j) {
        const int gi = base + j * TPB;
        vint4   s = src4[gi];
        vint4   d = dst4[gi];
        vfloat4 w = w4[gi];
        float g0, g1, g2, g3;
        if (MODE == 2) {
            g0 = fetch_direct(s.x, terrain, pop, mem);
            g1 = fetch_direct(s.y, terrain, pop, mem);
            g2 = fetch_direct(s.z, terrain, pop, mem);
            g3 = fetch_direct(s.w, terrain, pop, mem);
        } else {
            g0 = x[s.x]; g1 = x[s.y]; g2 = x[s.z]; g3 = x[s.w];
        }
        unsafeAtomicAdd(&acc[d.x], g0 * w.x);
        unsafeAtomicAdd(&acc[d.y], g1 * w.y);
        unsafeAtomicAdd(&acc[d.z], g2 * w.z);
        unsafeAtomicAdd(&acc[d.w], g3 * w.w);
    }
    __syncthreads();
    unsafeAtomicAdd(&outp[t],       acc[t]);
    unsafeAtomicAdd(&outp[t + TPB], acc[t + TPB]);
}

// ---------------------------------------------------------------
// Stage 2: out[c] = sum over 32 partial rows. Direct write.
// ---------------------------------------------------------------
__global__ __launch_bounds__(TPB) void reduce_kernel(
    const float* __restrict__ partials, float* __restrict__ out)
{
    const int c = blockIdx.x * TPB + threadIdx.x;   // 0..511
    float s = 0.0f;
#pragma unroll
    for (int r = 0; r < NACC; ++r)
        s += partials[(size_t)r * NOUT + c];
    out[c] = s;
}

extern "C" void kernel_launch(void* const* d_in, const int* in_sizes, int n_in,
                              void* d_out, int out_size, void* d_ws, size_t ws_size,
                              hipStream_t stream)
{
    const float* terrain = (const float*)d_in[0];
    const float* pop     = (const float*)d_in[1];
    const float* mem     = (const float*)d_in[2];
    const int*   src     = (const int*)d_in[3];
    const int*   dst     = (const int*)d_in[4];
    const float* w       = (const float*)d_in[5];
    float* out = (float*)d_out;

    const size_t X_BYTES  = (size_t)NIN * 4;                      // 1,179,652
    const size_t PART_OFF = 1179904;                              // 256B aligned
    const size_t NEED     = PART_OFF + (size_t)ACC_FLOATS * 4;    // ~1.25 MB

    float* x        = (float*)d_ws;
    float* partials = (float*)((char*)d_ws + PART_OFF);

    if (ws_size >= NEED) {
        build_x_kernel<<<(NIN + TPB - 1) / TPB, TPB, 0, stream>>>(
            terrain, pop, mem, x, partials);
        edge_kernel<<<NBLK_E, TPB, 0, stream>>>(
            (const vint4*)src, (const vint4*)dst, (const vfloat4*)w, x, partials);
        reduce_kernel<<<NOUT / TPB, TPB, 0, stream>>>(partials, out);
    } else if (ws_size >= X_BYTES) {
        build_x_kernel<<<(NIN + TPB - 1) / TPB, TPB, 0, stream>>>(
            terrain, pop, mem, x, (float*)d_ws);  // no partials room: reuse x head (unused)
        zero_out_kernel<<<2, TPB, 0, stream>>>(out);
        edge_fallback_kernel<1><<<NBLK_E, TPB, 0, stream>>>(
            (const vint4*)src, (const vint4*)dst, (const vfloat4*)w,
            x, terrain, pop, mem, out);
    } else {
        zero_out_kernel<<<2, TPB, 0, stream>>>(out);
        edge_fallback_kernel<2><<<NBLK_E, TPB, 0, stream>>>(
            (const vint4*)src, (const vint4*)dst, (const vfloat4*)w,
            nullptr, terrain, pop, mem, out);
    }
}